// Round 8
// baseline (83.477 us; speedup 1.0000x reference)
//
#include <hip/hip_runtime.h>

#define NRES  300
#define NTRJ  20
#define NBINS 34
#define PLANE (NTRJ * NRES * 3)      // 18000 floats per output plane
#define NJT   5                      // tiles of 64 (j for CB/O, i for H)
#define NB    5                      // trajectories per lane; 4 waves = 20
#define IC    2                      // i's per CB block
#define NCH   150                    // 300 / IC
#define TILEF (64 * NBINS)           // 2176 floats per staged gw row
#define TILE4 (TILEF / 4)            // 544 float4
#define IC2   20                     // i's (or j's) per HB block
#define NHB   15                     // 300 / IC2
// ws layout in planes of PLANE floats: CB partials [0,150), O [150,165), H [165,180)
#define OFF_O 150
#define OFF_H 165
#define WS_FLOATS ((size_t)(NCH + 2 * NHB) * PLANE)   // 12.96 MB

// ======================= CB distogram kernel ===============================
// Block = (j-tile 64, i-chunk of 2) x all 20 b (4 waves x NB=5).
// Per i: gw row coalesced float4 -> LDS (double-buffered, prefetch in regs),
// lane reads its 34 weights once, reuses across 5 trajectories in registers.
// No atomics, no shuffles: per-chunk partials stored plain to ws.
template <bool PART>
__global__ __launch_bounds__(256, 3)
void cb_kernel(const float* __restrict__ cCB, const float* __restrict__ gw,
               float* __restrict__ out, float* __restrict__ part) {
  __shared__ float wlds[2][TILEF];
  __shared__ float sCB[NTRJ * IC * 3];     // i-side CB coords for the chunk

  const int tid  = threadIdx.x;
  const int wv   = tid >> 6;
  const int lane = tid & 63;
  const int b0   = wv * NB;
  const int jt   = blockIdx.x % NJT;
  const int ch   = blockIdx.x / NJT;       // 0..NCH-1
  const int i0   = ch * IC;
  const int j    = jt * 64 + lane;
  const bool jv  = (j < NRES);
  const int jc   = jv ? j : NRES - 1;
  const int F4   = (jt == 4) ? ((NRES - 256) * NBINS) / 4 : TILE4;

  if (tid < NTRJ * IC * 3) {               // [b][ii][c]
    const int b = tid / (IC * 3), r = tid % (IC * 3);
    sCB[tid] = cCB[((b * NRES) + i0 + r / 3) * 3 + (r % 3)];
  }

  float pjx[NB], pjy[NB], pjz[NB];
  float acx[NB] = {}, acy[NB] = {}, acz[NB] = {};
#pragma unroll
  for (int q = 0; q < NB; ++q) {
    const float* p = cCB + ((size_t)((b0 + q) * NRES + jc)) * 3;
    pjx[q] = p[0]; pjy[q] = p[1]; pjz[q] = p[2];
  }

  float4 r4[3];
  {
    const float4* src = (const float4*)(gw + ((size_t)i0 * NRES + jt * 64) * NBINS);
#pragma unroll
    for (int q = 0; q < 3; ++q) {
      const int e = tid + q * 256;
      r4[q] = (e < F4) ? src[e] : make_float4(0.f, 0.f, 0.f, 0.f);
    }
  }

  int p = 0;
  for (int ii = 0; ii < IC; ++ii) {
    float4* dst = (float4*)wlds[p];
#pragma unroll
    for (int q = 0; q < 3; ++q) {
      const int e = tid + q * 256;
      if (e < TILE4) dst[e] = r4[q];
    }
    __syncthreads();
    if (ii + 1 < IC) {
      const float4* src =
          (const float4*)(gw + ((size_t)(i0 + ii + 1) * NRES + jt * 64) * NBINS);
#pragma unroll
      for (int q = 0; q < 3; ++q) {
        const int e = tid + q * 256;
        r4[q] = (e < F4) ? src[e] : make_float4(0.f, 0.f, 0.f, 0.f);
      }
    }

    float w[36];
    const float2* p2 = (const float2*)(wlds[p] + lane * NBINS);
#pragma unroll
    for (int k = 0; k < 17; ++k) { float2 v = p2[k]; w[2*k] = v.x; w[2*k+1] = v.y; }
    w[34] = 0.f; w[35] = 0.f;

#pragma unroll
    for (int q = 0; q < NB; ++q) {
      const float* pi = &sCB[((b0 + q) * IC + ii) * 3];   // LDS broadcast
      float dx = pjx[q] - pi[0], dy = pjy[q] - pi[1], dz = pjz[q] - pi[2];
      float d2 = fmaf(dx, dx, fmaf(dy, dy, dz * dz));
      d2 = fminf(fmaxf(d2, 0.01f), 1600.0f);              // d in [0.1, 40]
      float rinv = __frsqrt_rn(d2);
      float d    = d2 * rinv;

      // g_k = exp(-0.32*dfm^2); ratio recurrence, 3 independent chains
      float dA = d - 3.75f, dB = d - 9.75f, dC = d - 15.75f;
      float gA = __expf(-0.32f * dA * dA), mA = __expf(fmaf(0.32f, dA, -0.08f));
      float gB = __expf(-0.32f * dB * dB), mB = __expf(fmaf(0.32f, dB, -0.08f));
      float gC = __expf(-0.32f * dC * dC), mC = __expf(fmaf(0.32f, dC, -0.08f));
      float s0 = 0.f, s1 = 0.f, s2 = 0.f;
#pragma unroll
      for (int k = 0; k < 12; ++k) {
        s0 = fmaf(w[k]      * dA, gA, s0); gA *= mA; mA *= 0.85214379f; dA -= 0.5f;
        s1 = fmaf(w[k + 12] * dB, gB, s1); gB *= mB; mB *= 0.85214379f; dB -= 0.5f;
        s2 = fmaf(w[k + 24] * dC, gC, s2); gC *= mC; mC *= 0.85214379f; dC -= 0.5f;
      }
      float cf = 76.8f * ((s0 + s1) + s2) * rinv;         // 150 / sigma^3
      acx[q] = fmaf(cf, dx, acx[q]);
      acy[q] = fmaf(cf, dy, acy[q]);
      acz[q] = fmaf(cf, dz, acz[q]);
    }
    p ^= 1;
  }

  if (jv) {
    if constexpr (PART) {
      float* pc = part + (size_t)ch * PLANE;
#pragma unroll
      for (int q = 0; q < NB; ++q) {
        const int base = ((b0 + q) * NRES + j) * 3;
        pc[base + 0] = acx[q]; pc[base + 1] = acy[q]; pc[base + 2] = acz[q];
      }
    } else {
      float* accCB = out + 3 * PLANE;
#pragma unroll
      for (int q = 0; q < NB; ++q) {
        const int base = ((b0 + q) * NRES + j) * 3;
        atomicAdd(&accCB[base + 0], acx[q]);
        atomicAdd(&accCB[base + 1], acy[q]);
        atomicAdd(&accCB[base + 2], acz[q]);
      }
    }
  }
}

// ======================= HB restraint kernel ===============================
// Half A (accs_O): lane = j, serial over 20 i's (hmin/hmax rows coalesced).
// Half B (accs_H): lane = i, serial over 20 j's; hmin/hmax tile transposed
// through LDS so the per-lane read is conflict-free. Register accumulation,
// partials to ws. No shuffles, no atomics.
template <bool PART>
__global__ __launch_bounds__(256, 4)
void hb_kernel(const float* __restrict__ cO, const float* __restrict__ cH,
               const float* __restrict__ hmin, const float* __restrict__ hmax,
               float* __restrict__ out, float* __restrict__ part) {
  const int tid  = threadIdx.x;
  const int wv   = tid >> 6;
  const int lane = tid & 63;
  const int b0   = wv * NB;

  if (blockIdx.x < NJT * NHB) {
    // ---------------- accs_O[b,j] = +sum_i pair_hb ----------------
    __shared__ float sH[NTRJ * IC2 * 3];
    const int jt  = blockIdx.x % NJT;
    const int ich = blockIdx.x / NJT;
    const int i0  = ich * IC2;
    const int j   = jt * 64 + lane;
    const bool jv = (j < NRES);
    const int jc  = jv ? j : NRES - 1;

    for (int e = tid; e < NTRJ * IC2 * 3; e += 256) {
      const int b = e / (IC2 * 3), r = e % (IC2 * 3);
      sH[e] = cH[((b * NRES) + i0 + r / 3) * 3 + (r % 3)];
    }
    float pox[NB], poy[NB], poz[NB];
    float aox[NB] = {}, aoy[NB] = {}, aoz[NB] = {};
#pragma unroll
    for (int q = 0; q < NB; ++q) {
      const float* o = cO + ((size_t)((b0 + q) * NRES + jc)) * 3;
      pox[q] = o[0]; poy[q] = o[1]; poz[q] = o[2];
    }
    __syncthreads();

    for (int ii = 0; ii < IC2; ++ii) {
      const int i = i0 + ii;
      const float hmn = hmin[i * NRES + jc];
      const float hmx = hmax[i * NRES + jc];
#pragma unroll
      for (int q = 0; q < NB; ++q) {
        const float* ph = &sH[((b0 + q) * IC2 + ii) * 3];
        float ex = pox[q] - ph[0], ey = poy[q] - ph[1], ez = poz[q] - ph[2];
        float e2 = fmaf(ex, ex, fmaf(ey, ey, ez * ez));
        e2 = fminf(fmaxf(e2, 0.01f), 1600.0f);
        float rh = __frsqrt_rn(e2);
        float dh = e2 * rh;
        float vmin = fmaxf(hmn - dh, 0.0f);
        float vmax = fmaxf(dh - hmx, 0.0f);
        float fmn = 15.0f * vmin;
        float fmx = (vmax > 0.0f) ? 5.0f * __powf(vmax, 0.75f) : 0.0f;
        float ff = (fmn - fmx) * rh;
        aox[q] = fmaf(ff, ex, aox[q]);
        aoy[q] = fmaf(ff, ey, aoy[q]);
        aoz[q] = fmaf(ff, ez, aoz[q]);
      }
    }
    if (jv) {
      if constexpr (PART) {
        float* po2 = part + (size_t)(OFF_O + ich) * PLANE;
#pragma unroll
        for (int q = 0; q < NB; ++q) {
          const int base = ((b0 + q) * NRES + j) * 3;
          po2[base + 0] = aox[q]; po2[base + 1] = aoy[q]; po2[base + 2] = aoz[q];
        }
      } else {
        float* accO = out + 2 * PLANE;
#pragma unroll
        for (int q = 0; q < NB; ++q) {
          const int base = ((b0 + q) * NRES + j) * 3;
          atomicAdd(&accO[base + 0], aox[q]);
          atomicAdd(&accO[base + 1], aoy[q]);
          atomicAdd(&accO[base + 2], aoz[q]);
        }
      }
    }
  } else {
    // ---------------- accs_H[b,i] = -sum_j pair_hb ----------------
    __shared__ float tmn[IC2][64], tmx[IC2][64];
    __shared__ float sO[NTRJ * IC2 * 3];
    const int bx2 = blockIdx.x - NJT * NHB;
    const int it  = bx2 % NJT;
    const int jch = bx2 / NJT;
    const int j0  = jch * IC2;
    const int i   = it * 64 + lane;
    const bool iv = (i < NRES);
    const int icl = iv ? i : NRES - 1;

    for (int e = tid; e < 64 * IC2; e += 256) {
      const int row = e / IC2, col = e % IC2;          // row = i-off, col = j-off
      int ig = it * 64 + row; if (ig > NRES - 1) ig = NRES - 1;
      tmn[col][row] = hmin[ig * NRES + j0 + col];
      tmx[col][row] = hmax[ig * NRES + j0 + col];
    }
    for (int e = tid; e < NTRJ * IC2 * 3; e += 256) {
      const int b = e / (IC2 * 3), r = e % (IC2 * 3);
      sO[e] = cO[((b * NRES) + j0 + r / 3) * 3 + (r % 3)];
    }
    float phx[NB], phy[NB], phz[NB];
    float ahx[NB] = {}, ahy[NB] = {}, ahz[NB] = {};
#pragma unroll
    for (int q = 0; q < NB; ++q) {
      const float* h = cH + ((size_t)((b0 + q) * NRES + icl)) * 3;
      phx[q] = h[0]; phy[q] = h[1]; phz[q] = h[2];
    }
    __syncthreads();

    for (int jj = 0; jj < IC2; ++jj) {
      const float hmn = tmn[jj][lane];
      const float hmx = tmx[jj][lane];
#pragma unroll
      for (int q = 0; q < NB; ++q) {
        const float* po = &sO[((b0 + q) * IC2 + jj) * 3];
        float ex = po[0] - phx[q], ey = po[1] - phy[q], ez = po[2] - phz[q];
        float e2 = fmaf(ex, ex, fmaf(ey, ey, ez * ez));
        e2 = fminf(fmaxf(e2, 0.01f), 1600.0f);
        float rh = __frsqrt_rn(e2);
        float dh = e2 * rh;
        float vmin = fmaxf(hmn - dh, 0.0f);
        float vmax = fmaxf(dh - hmx, 0.0f);
        float fmn = 15.0f * vmin;
        float fmx = (vmax > 0.0f) ? 5.0f * __powf(vmax, 0.75f) : 0.0f;
        float ff = (fmn - fmx) * rh;
        ahx[q] = fmaf(-ff, ex, ahx[q]);
        ahy[q] = fmaf(-ff, ey, ahy[q]);
        ahz[q] = fmaf(-ff, ez, ahz[q]);
      }
    }
    if (iv) {
      if constexpr (PART) {
        float* ph2 = part + (size_t)(OFF_H + jch) * PLANE;
#pragma unroll
        for (int q = 0; q < NB; ++q) {
          const int base = ((b0 + q) * NRES + i) * 3;
          ph2[base + 0] = ahx[q]; ph2[base + 1] = ahy[q]; ph2[base + 2] = ahz[q];
        }
      } else {
        float* accH = out + 4 * PLANE;
#pragma unroll
        for (int q = 0; q < NB; ++q) {
          const int base = ((b0 + q) * NRES + i) * 3;
          atomicAdd(&accH[base + 0], ahx[q]);
          atomicAdd(&accH[base + 1], ahy[q]);
          atomicAdd(&accH[base + 2], ahz[q]);
        }
      }
    }
  }
}

// ===================== final reduce: writes ALL 5 planes ====================
__global__ __launch_bounds__(256)
void reduce_all(const float* __restrict__ part, float* __restrict__ out) {
  const int t = blockIdx.x * 256 + threadIdx.x;
  if (t >= PLANE) return;
  float s0 = 0.f, s1 = 0.f;
  const float* pc = part + t;
#pragma unroll 5
  for (int ch = 0; ch < NCH; ch += 2) {
    s0 += pc[(size_t)ch * PLANE];
    s1 += pc[(size_t)(ch + 1) * PLANE];
  }
  float so = 0.f, sh = 0.f;
#pragma unroll
  for (int ch = 0; ch < NHB; ++ch) {
    so += pc[(size_t)(OFF_O + ch) * PLANE];
    sh += pc[(size_t)(OFF_H + ch) * PLANE];
  }
  out[0 * PLANE + t] = 0.f;       // accs_N (K_ANG_HB_GEN == 0)
  out[1 * PLANE + t] = 0.f;       // accs_C
  out[2 * PLANE + t] = so;        // accs_O
  out[3 * PLANE + t] = s0 + s1;   // accs_CB
  out[4 * PLANE + t] = sh;        // accs_H
}

extern "C" void kernel_launch(void* const* d_in, const int* in_sizes, int n_in,
                              void* d_out, int out_size, void* d_ws, size_t ws_size,
                              hipStream_t stream) {
  // input order per setup_inputs(): N, C, O, CB, H, gaussian_weights, hb_min, hb_max
  const float* cO  = (const float*)d_in[2];
  const float* cCB = (const float*)d_in[3];
  const float* cH  = (const float*)d_in[4];
  const float* gw  = (const float*)d_in[5];
  const float* hmn = (const float*)d_in[6];
  const float* hmx = (const float*)d_in[7];
  float* out = (float*)d_out;

  if (ws_size >= WS_FLOATS * sizeof(float)) {
    float* part = (float*)d_ws;
    cb_kernel<true><<<dim3(NJT * NCH), dim3(256), 0, stream>>>(cCB, gw, out, part);
    hb_kernel<true><<<dim3(2 * NJT * NHB), dim3(256), 0, stream>>>(
        cO, cH, hmn, hmx, out, part);
    reduce_all<<<dim3((PLANE + 255) / 256), dim3(256), 0, stream>>>(part, out);
  } else {
    hipMemsetAsync(out, 0, (size_t)out_size * sizeof(float), stream);
    cb_kernel<false><<<dim3(NJT * NCH), dim3(256), 0, stream>>>(cCB, gw, out, nullptr);
    hb_kernel<false><<<dim3(2 * NJT * NHB), dim3(256), 0, stream>>>(
        cO, cH, hmn, hmx, out, nullptr);
  }
}

// Round 13
// 49.363 us; speedup vs baseline: 1.6911x; 1.6911x over previous
//
#include <hip/hip_runtime.h>

#define NRES  300
#define NTRJ  20
#define NBINS 34
#define PLANE (NTRJ * NRES * 3)      // 18000 floats per output plane
#define TILEF (64 * NBINS)           // 2176 floats per staged gw row tile
#define TILE4 (TILEF / 4)            // 544 float4
#define NHP   20                     // H partial planes (5 jt x 4 waves)

#define EXP2F(x) __builtin_exp2f(x)
#define LOG2F(x) __builtin_log2f(x)

// sum over the 16-lane jsub group (masks 1,2,4,8 stay within the group)
__device__ __forceinline__ float g16sum(float v) {
#pragma unroll
  for (int m = 1; m < 16; m <<= 1) v += __shfl_xor(v, m, 64);
  return v;
}

// One fused kernel: CB distogram + HB O-sum + HB H-sum.
// Lane = (bsub 0..3, jsub 0..15); wave wv covers j in [jt*64+wv*16, +16) x all
// 20 trajectories (b = bsub*5+q, q<5 register-blocked). gw row staged
// coalesced float4 -> LDS (double-buffered, reg prefetch); per-lane weights
// reused across 5 b. CB/O accumulate in registers -> plain per-chunk partial
// stores; H reduced with 4 xor-shuffles over the jsub group -> plain store
// into per-(jt,wave) partial plane. PART path has ZERO atomics.
template <int IC, bool PART>
__global__ __launch_bounds__(256)
void force_fused(const float* __restrict__ cO, const float* __restrict__ cCB,
                 const float* __restrict__ cH, const float* __restrict__ gw,
                 const float* __restrict__ hmin, const float* __restrict__ hmax,
                 float* __restrict__ out, float* __restrict__ part) {
  constexpr int NCH = NRES / IC;
  __shared__ float wlds[2][TILEF];
  __shared__ float sCB[NTRJ * IC * 3];
  __shared__ float sHH[NTRJ * IC * 3];

  const int tid  = threadIdx.x;
  const int wv   = tid >> 6;
  const int lane = tid & 63;
  const int bsub = lane >> 4;
  const int jsub = lane & 15;
  const int jt   = blockIdx.x % 5;
  const int ch   = blockIdx.x / 5;         // 0..NCH-1
  const int i0   = ch * IC;
  const int j    = jt * 64 + wv * 16 + jsub;
  const bool jv  = (j < NRES);
  const int jc   = jv ? j : NRES - 1;
  const int F4   = (jt == 4) ? ((NRES - 256) * NBINS) / 4 : TILE4;

  // stage i-side coords for the chunk: [b][ii][c]
  for (int e = tid; e < NTRJ * IC * 3; e += 256) {
    const int b = e / (IC * 3), r = e % (IC * 3);
    sCB[e] = cCB[((b * NRES) + i0 + r / 3) * 3 + (r % 3)];
    sHH[e] = cH [((b * NRES) + i0 + r / 3) * 3 + (r % 3)];
  }

  float pjx[5], pjy[5], pjz[5], pox[5], poy[5], poz[5];
  float acx[5] = {}, acy[5] = {}, acz[5] = {};   // accs_CB[b,j] partials
  float aox[5] = {}, aoy[5] = {}, aoz[5] = {};   // accs_O [b,j] partials
#pragma unroll
  for (int q = 0; q < 5; ++q) {
    const int b = bsub * 5 + q;
    const float* p = cCB + ((size_t)(b * NRES + jc)) * 3;
    pjx[q] = p[0]; pjy[q] = p[1]; pjz[q] = p[2];
    const float* o = cO + ((size_t)(b * NRES + jc)) * 3;
    pox[q] = o[0]; poy[q] = o[1]; poz[q] = o[2];
  }

  // prefetch first gw row tile (byte offset is always 16B-aligned: row index
  // i*300 + jt*64 is even, 2 rows = 272B)
  float4 r4[3];
  {
    const float4* src = (const float4*)(gw + ((size_t)i0 * NRES + jt * 64) * NBINS);
#pragma unroll
    for (int u = 0; u < 3; ++u) {
      const int e = tid + u * 256;
      r4[u] = (e < F4) ? src[e] : make_float4(0.f, 0.f, 0.f, 0.f);
    }
  }

  int p = 0;
  for (int ii = 0; ii < IC; ++ii) {
    const int i = i0 + ii;
    float4* dst = (float4*)wlds[p];
#pragma unroll
    for (int u = 0; u < 3; ++u) {
      const int e = tid + u * 256;
      if (e < TILE4) dst[e] = r4[u];
    }
    __syncthreads();
    if (ii + 1 < IC) {
      const float4* src =
          (const float4*)(gw + ((size_t)(i + 1) * NRES + jt * 64) * NBINS);
#pragma unroll
      for (int u = 0; u < 3; ++u) {
        const int e = tid + u * 256;
        r4[u] = (e < F4) ? src[e] : make_float4(0.f, 0.f, 0.f, 0.f);
      }
    }

    // my j's weights (16 rows/wave, 4-way broadcast, conflict-free b64)
    float w[36];
    const float2* p2 = (const float2*)(wlds[p] + (wv * 16 + jsub) * NBINS);
#pragma unroll
    for (int k = 0; k < 17; ++k) { float2 v = p2[k]; w[2*k] = v.x; w[2*k+1] = v.y; }
    w[34] = 0.f; w[35] = 0.f;

    const float hmn = hmin[i * NRES + jc];
    const float hmx = hmax[i * NRES + jc];

#pragma unroll
    for (int q = 0; q < 5; ++q) {
      const int b = bsub * 5 + q;
      const float* pi = &sCB[(b * IC + ii) * 3];
      const float* ph = &sHH[(b * IC + ii) * 3];

      // ---- CB distogram: 3 x 12-bin exp2 ratio-recurrence chains ----
      float dx = pjx[q] - pi[0], dy = pjy[q] - pi[1], dz = pjz[q] - pi[2];
      float d2 = fmaf(dx, dx, fmaf(dy, dy, dz * dz));
      d2 = fminf(fmaxf(d2, 0.01f), 1600.0f);          // d in [0.1, 40]
      float rinv = __frsqrt_rn(d2);
      float d    = d2 * rinv;
      // g_k = 2^(-0.46166241*dfm^2) = exp(-0.32*dfm^2)
      float dA = d - 3.75f, dB = d - 9.75f, dC = d - 15.75f;
      float gA = EXP2F(-0.46166241f * dA * dA);
      float mA = EXP2F(fmaf(0.46166241f, dA, -0.11541560f));
      float gB = EXP2F(-0.46166241f * dB * dB);
      float mB = EXP2F(fmaf(0.46166241f, dB, -0.11541560f));
      float gC = EXP2F(-0.46166241f * dC * dC);
      float mC = EXP2F(fmaf(0.46166241f, dC, -0.11541560f));
      float s0 = 0.f, s1 = 0.f, s2 = 0.f;
#pragma unroll
      for (int k = 0; k < 12; ++k) {
        s0 = fmaf(w[k]      * dA, gA, s0); gA *= mA; mA *= 0.85214379f; dA -= 0.5f;
        s1 = fmaf(w[k + 12] * dB, gB, s1); gB *= mB; mB *= 0.85214379f; dB -= 0.5f;
        s2 = fmaf(w[k + 24] * dC, gC, s2); gC *= mC; mC *= 0.85214379f; dC -= 0.5f;
      }
      float cf = 76.8f * ((s0 + s1) + s2) * rinv;     // 150 / sigma^3
      acx[q] = fmaf(cf, dx, acx[q]);
      acy[q] = fmaf(cf, dy, acy[q]);
      acz[q] = fmaf(cf, dz, acz[q]);

      // ---- HB restraint (O_j - H_i) ----
      float ex = pox[q] - ph[0], ey = poy[q] - ph[1], ez = poz[q] - ph[2];
      float e2 = fmaf(ex, ex, fmaf(ey, ey, ez * ez));
      e2 = fminf(fmaxf(e2, 0.01f), 1600.0f);
      float rh = __frsqrt_rn(e2);
      float dh = e2 * rh;
      float vmin = fmaxf(hmn - dh, 0.0f);
      float vmax = fmaxf(dh - hmx, 0.0f);
      float fmn = 15.0f * vmin;                       // 3*5*v^1
      float fmx = (vmax > 0.0f) ? 5.0f * EXP2F(0.75f * LOG2F(vmax)) : 0.0f;
      float ff = (fmn - fmx) * rh;
      float qx = ff * ex, qy = ff * ey, qz = ff * ez; // pair_hb
      aox[q] += qx; aoy[q] += qy; aoz[q] += qz;       // accs_O (+sum over i)

      // accs_H[b,i] = -sum_j pair_hb: 16-lane group sum, one plain store
      float sx = g16sum(jv ? qx : 0.f);
      float sy = g16sum(jv ? qy : 0.f);
      float sz = g16sum(jv ? qz : 0.f);
      if (jsub == 0) {
        if constexpr (PART) {
          float* hp = part + ((size_t)(2 * NCH + jt * 4 + wv)) * PLANE +
                      ((size_t)b * NRES + i) * 3;
          hp[0] = -sx; hp[1] = -sy; hp[2] = -sz;
        } else {
          atomicAdd(&out[4 * PLANE + (b * NRES + i) * 3 + 0], -sx);
          atomicAdd(&out[4 * PLANE + (b * NRES + i) * 3 + 1], -sy);
          atomicAdd(&out[4 * PLANE + (b * NRES + i) * 3 + 2], -sz);
        }
      }
    }
    p ^= 1;
  }

  if (jv) {
    if constexpr (PART) {
      float* pc  = part + (size_t)ch * PLANE;
      float* po2 = part + (size_t)(NCH + ch) * PLANE;
#pragma unroll
      for (int q = 0; q < 5; ++q) {
        const int base = ((bsub * 5 + q) * NRES + j) * 3;
        pc[base + 0]  = acx[q]; pc[base + 1]  = acy[q]; pc[base + 2]  = acz[q];
        po2[base + 0] = aox[q]; po2[base + 1] = aoy[q]; po2[base + 2] = aoz[q];
      }
    } else {
#pragma unroll
      for (int q = 0; q < 5; ++q) {
        const int base = ((bsub * 5 + q) * NRES + j) * 3;
        atomicAdd(&out[3 * PLANE + base + 0], acx[q]);
        atomicAdd(&out[3 * PLANE + base + 1], acy[q]);
        atomicAdd(&out[3 * PLANE + base + 2], acz[q]);
        atomicAdd(&out[2 * PLANE + base + 0], aox[q]);
        atomicAdd(&out[2 * PLANE + base + 1], aoy[q]);
        atomicAdd(&out[2 * PLANE + base + 2], aoz[q]);
      }
    }
  }
}

// writes ALL 5 output planes (N = C = 0); sums NCH CB, NCH O, 20 H partials
template <int NCH>
__global__ __launch_bounds__(256)
void reduce_all(const float* __restrict__ part, float* __restrict__ out) {
  const int t = blockIdx.x * 256 + threadIdx.x;
  if (t >= PLANE) return;
  const float* pc = part + t;
  const float* po = part + (size_t)NCH * PLANE + t;
  const float* ph = part + (size_t)2 * NCH * PLANE + t;
  float scb = 0.f, so = 0.f, sh = 0.f;
#pragma unroll 5
  for (int c = 0; c < NCH; ++c) {
    scb += pc[(size_t)c * PLANE];
    so  += po[(size_t)c * PLANE];
  }
#pragma unroll
  for (int c = 0; c < NHP; ++c) sh += ph[(size_t)c * PLANE];
  out[0 * PLANE + t] = 0.f;   // accs_N  (K_ANG_HB_GEN == 0)
  out[1 * PLANE + t] = 0.f;   // accs_C
  out[2 * PLANE + t] = so;    // accs_O
  out[3 * PLANE + t] = scb;   // accs_CB
  out[4 * PLANE + t] = sh;    // accs_H
}

extern "C" void kernel_launch(void* const* d_in, const int* in_sizes, int n_in,
                              void* d_out, int out_size, void* d_ws, size_t ws_size,
                              hipStream_t stream) {
  // input order per setup_inputs(): N, C, O, CB, H, gaussian_weights, hb_min, hb_max
  const float* cO  = (const float*)d_in[2];
  const float* cCB = (const float*)d_in[3];
  const float* cH  = (const float*)d_in[4];
  const float* gw  = (const float*)d_in[5];
  const float* hmn = (const float*)d_in[6];
  const float* hmx = (const float*)d_in[7];
  float* out  = (float*)d_out;
  float* part = (float*)d_ws;

  const size_t plane_b = (size_t)PLANE * sizeof(float);
  const int nred = (PLANE + 255) / 256;

  if (ws_size >= (2 * 150 + NHP) * plane_b) {          // 23.04 MB: IC=2, 750 blocks
    force_fused<2, true><<<dim3(5 * 150), dim3(256), 0, stream>>>(
        cO, cCB, cH, gw, hmn, hmx, out, part);
    reduce_all<150><<<dim3(nred), dim3(256), 0, stream>>>(part, out);
  } else if (ws_size >= (2 * 75 + NHP) * plane_b) {    // 12.24 MB: IC=4, 375 blocks
    force_fused<4, true><<<dim3(5 * 75), dim3(256), 0, stream>>>(
        cO, cCB, cH, gw, hmn, hmx, out, part);
    reduce_all<75><<<dim3(nred), dim3(256), 0, stream>>>(part, out);
  } else {                                             // atomic fallback
    (void)hipMemsetAsync(out, 0, (size_t)out_size * sizeof(float), stream);
    force_fused<4, false><<<dim3(5 * 75), dim3(256), 0, stream>>>(
        cO, cCB, cH, gw, hmn, hmx, out, nullptr);
  }
}

// Round 14
// 39.788 us; speedup vs baseline: 2.0981x; 1.2407x over previous
//
#include <hip/hip_runtime.h>

#define NRES  300
#define NTRJ  20
#define NBINS 34
#define PLANE (NTRJ * NRES * 3)      // 18000 floats per output plane
#define IC    2                      // i's per block
#define NCH   150                    // 300 / IC
#define NHP   20                     // H partial planes (5 jt x 4 waves)
#define WROW  544                    // 16 rows x 34 floats (one wave tile)
#define WF2   272                    // float2 per wave tile
#define NRED  ((PLANE + 255) / 256)  // 71

#define EXP2F(x) __builtin_exp2f(x)
#define LOG2F(x) __builtin_log2f(x)

// sum over the 16-lane jsub group (masks 1,2,4,8 stay within the group)
__device__ __forceinline__ float g16sum(float v) {
#pragma unroll
  for (int m = 1; m < 16; m <<= 1) v += __shfl_xor(v, m, 64);
  return v;
}

// Fused CB + HB(O) + HB(H) kernel. Lane = (bsub 0..3, jsub 0..15); wave wv
// owns j in [jt*64+wv*16, +16); b = bsub*5+q register-blocked (NB=5).
// BARRIER-FREE main loop: each wave stages its OWN 16 gw rows (544 contiguous
// floats) into a wave-private LDS buffer via coalesced float2 loads, so the
// 4 waves free-run and stagger their LDS/VMEM/VALU phases. CB/O partials are
// plain per-chunk stores; H uses a 16-lane shuffle sum + plain store into a
// per-(jt,wave) plane. PART path has ZERO atomics.
template <bool PART>
__global__ __launch_bounds__(256)
void force_fused(const float* __restrict__ cO, const float* __restrict__ cCB,
                 const float* __restrict__ cH, const float* __restrict__ gw,
                 const float* __restrict__ hmin, const float* __restrict__ hmax,
                 float* __restrict__ out, float* __restrict__ part) {
  __shared__ float wbuf[4][WROW];          // wave-private gw tiles
  __shared__ float sCB[NTRJ * IC * 3];
  __shared__ float sHH[NTRJ * IC * 3];

  const int tid  = threadIdx.x;
  const int wv   = tid >> 6;
  const int lane = tid & 63;
  const int bsub = lane >> 4;
  const int jsub = lane & 15;
  const int jt   = blockIdx.x % 5;
  const int ch   = blockIdx.x / 5;         // 0..NCH-1
  const int i0   = ch * IC;
  const int j0w  = jt * 64 + wv * 16;      // wave's first j row
  const int j    = j0w + jsub;
  const bool jv  = (j < NRES);
  const int jc   = jv ? j : NRES - 1;
  // valid float2 elements in this wave's tile (rows are contiguous in gw)
  const int nrow = min(16, max(0, NRES - j0w));
  const int E2   = nrow * 17;

  // stage i-side coords for the chunk: [b][ii][c]; single barrier, then none
  for (int e = tid; e < NTRJ * IC * 3; e += 256) {
    const int b = e / (IC * 3), r = e % (IC * 3);
    sCB[e] = cCB[((b * NRES) + i0 + r / 3) * 3 + (r % 3)];
    sHH[e] = cH [((b * NRES) + i0 + r / 3) * 3 + (r % 3)];
  }
  __syncthreads();

  float pjx[5], pjy[5], pjz[5], pox[5], poy[5], poz[5];
  float acx[5] = {}, acy[5] = {}, acz[5] = {};   // accs_CB[b,j] partials
  float aox[5] = {}, aoy[5] = {}, aoz[5] = {};   // accs_O [b,j] partials
#pragma unroll
  for (int q = 0; q < 5; ++q) {
    const int b = bsub * 5 + q;
    const float* p = cCB + ((size_t)(b * NRES + jc)) * 3;
    pjx[q] = p[0]; pjy[q] = p[1]; pjz[q] = p[2];
    const float* o = cO + ((size_t)(b * NRES + jc)) * 3;
    pox[q] = o[0]; poy[q] = o[1]; poz[q] = o[2];
  }

  // prefetch wave tile for i0 (linear coalesced float2 copy, 8B-aligned)
  float2 r2[5];
  {
    const float2* src = (const float2*)gw + ((size_t)i0 * NRES + j0w) * 17;
#pragma unroll
    for (int u = 0; u < 5; ++u) {
      const int e = lane + u * 64;
      r2[u] = (e < E2) ? src[e] : make_float2(0.f, 0.f);
    }
  }

  float2* wd = (float2*)&wbuf[wv][0];
  for (int ii = 0; ii < IC; ++ii) {
    const int i = i0 + ii;
    // wave-private stage (no cross-wave barrier; DS pipe is in-order per wave)
#pragma unroll
    for (int u = 0; u < 5; ++u) {
      const int e = lane + u * 64;
      if (e < WF2) wd[e] = r2[u];
    }
    // prefetch next tile while this one is consumed
    if (ii + 1 < IC) {
      const float2* src =
          (const float2*)gw + ((size_t)(i + 1) * NRES + j0w) * 17;
#pragma unroll
      for (int u = 0; u < 5; ++u) {
        const int e = lane + u * 64;
        r2[u] = (e < E2) ? src[e] : make_float2(0.f, 0.f);
      }
    }

    // my j's weights: 17 x ds_read_b64, stride 136B -> conflict-free,
    // 4-way bsub broadcast
    float w[36];
    const float2* p2 = (const float2*)&wbuf[wv][jsub * NBINS];
#pragma unroll
    for (int k = 0; k < 17; ++k) { float2 v = p2[k]; w[2*k] = v.x; w[2*k+1] = v.y; }
    w[34] = 0.f; w[35] = 0.f;

    const float hmn = hmin[i * NRES + jc];
    const float hmx = hmax[i * NRES + jc];

#pragma unroll
    for (int q = 0; q < 5; ++q) {
      const int b = bsub * 5 + q;
      const float* pi = &sCB[(b * IC + ii) * 3];
      const float* ph = &sHH[(b * IC + ii) * 3];

      // ---- CB distogram: 3 x 12-bin exp2 ratio-recurrence chains ----
      float dx = pjx[q] - pi[0], dy = pjy[q] - pi[1], dz = pjz[q] - pi[2];
      float d2 = fmaf(dx, dx, fmaf(dy, dy, dz * dz));
      d2 = fminf(fmaxf(d2, 0.01f), 1600.0f);          // d in [0.1, 40]
      float rinv = __frsqrt_rn(d2);
      float d    = d2 * rinv;
      // g_k = 2^(-0.46166241*dfm^2) = exp(-0.32*dfm^2)
      float dA = d - 3.75f, dB = d - 9.75f, dC = d - 15.75f;
      float gA = EXP2F(-0.46166241f * dA * dA);
      float mA = EXP2F(fmaf(0.46166241f, dA, -0.11541560f));
      float gB = EXP2F(-0.46166241f * dB * dB);
      float mB = EXP2F(fmaf(0.46166241f, dB, -0.11541560f));
      float gC = EXP2F(-0.46166241f * dC * dC);
      float mC = EXP2F(fmaf(0.46166241f, dC, -0.11541560f));
      float s0 = 0.f, s1 = 0.f, s2 = 0.f;
#pragma unroll
      for (int k = 0; k < 12; ++k) {
        s0 = fmaf(w[k]      * dA, gA, s0); gA *= mA; mA *= 0.85214379f; dA -= 0.5f;
        s1 = fmaf(w[k + 12] * dB, gB, s1); gB *= mB; mB *= 0.85214379f; dB -= 0.5f;
        s2 = fmaf(w[k + 24] * dC, gC, s2); gC *= mC; mC *= 0.85214379f; dC -= 0.5f;
      }
      float cf = 76.8f * ((s0 + s1) + s2) * rinv;     // 150 / sigma^3
      acx[q] = fmaf(cf, dx, acx[q]);
      acy[q] = fmaf(cf, dy, acy[q]);
      acz[q] = fmaf(cf, dz, acz[q]);

      // ---- HB restraint (O_j - H_i) ----
      float ex = pox[q] - ph[0], ey = poy[q] - ph[1], ez = poz[q] - ph[2];
      float e2 = fmaf(ex, ex, fmaf(ey, ey, ez * ez));
      e2 = fminf(fmaxf(e2, 0.01f), 1600.0f);
      float rh = __frsqrt_rn(e2);
      float dh = e2 * rh;
      float vmin = fmaxf(hmn - dh, 0.0f);
      float vmax = fmaxf(dh - hmx, 0.0f);
      float fmn = 15.0f * vmin;                       // 3*5*v^1
      float fmx = (vmax > 0.0f) ? 5.0f * EXP2F(0.75f * LOG2F(vmax)) : 0.0f;
      float ff = (fmn - fmx) * rh;
      float qx = ff * ex, qy = ff * ey, qz = ff * ez; // pair_hb
      aox[q] += qx; aoy[q] += qy; aoz[q] += qz;       // accs_O (+sum over i)

      // accs_H[b,i] = -sum_j pair_hb: 16-lane group sum, one plain store
      float sx = g16sum(jv ? qx : 0.f);
      float sy = g16sum(jv ? qy : 0.f);
      float sz = g16sum(jv ? qz : 0.f);
      if (jsub == 0) {
        if constexpr (PART) {
          float* hp = part + ((size_t)(2 * NCH + jt * 4 + wv)) * PLANE +
                      ((size_t)b * NRES + i) * 3;
          hp[0] = -sx; hp[1] = -sy; hp[2] = -sz;
        } else {
          atomicAdd(&out[4 * PLANE + (b * NRES + i) * 3 + 0], -sx);
          atomicAdd(&out[4 * PLANE + (b * NRES + i) * 3 + 1], -sy);
          atomicAdd(&out[4 * PLANE + (b * NRES + i) * 3 + 2], -sz);
        }
      }
    }
  }

  if (jv) {
    if constexpr (PART) {
      float* pc  = part + (size_t)ch * PLANE;
      float* po2 = part + (size_t)(NCH + ch) * PLANE;
#pragma unroll
      for (int q = 0; q < 5; ++q) {
        const int base = ((bsub * 5 + q) * NRES + j) * 3;
        pc[base + 0]  = acx[q]; pc[base + 1]  = acy[q]; pc[base + 2]  = acz[q];
        po2[base + 0] = aox[q]; po2[base + 1] = aoy[q]; po2[base + 2] = aoz[q];
      }
    } else {
#pragma unroll
      for (int q = 0; q < 5; ++q) {
        const int base = ((bsub * 5 + q) * NRES + j) * 3;
        atomicAdd(&out[3 * PLANE + base + 0], acx[q]);
        atomicAdd(&out[3 * PLANE + base + 1], acy[q]);
        atomicAdd(&out[3 * PLANE + base + 2], acz[q]);
        atomicAdd(&out[2 * PLANE + base + 0], aox[q]);
        atomicAdd(&out[2 * PLANE + base + 1], aoy[q]);
        atomicAdd(&out[2 * PLANE + base + 2], aoz[q]);
      }
    }
  }
}

// Segmented reduce: 7 segments x NRED blocks; each block sums <=50 planes for
// its 256 elements with 10 independent accumulator chains (latency-parallel),
// then one atomicAdd per element into the (pre-zeroed) output plane.
__global__ __launch_bounds__(256)
void reduce_seg(const float* __restrict__ part, float* __restrict__ out) {
  const int seg  = blockIdx.x / NRED;      // 0..6
  const int tblk = blockIdx.x % NRED;
  const int t    = tblk * 256 + threadIdx.x;
  if (t >= PLANE) return;

  int c0, cnt;
  float* dst;
  if (seg < 3)      { c0 = seg * 50;             cnt = 50; dst = out + 3 * PLANE; }
  else if (seg < 6) { c0 = NCH + (seg - 3) * 50; cnt = 50; dst = out + 2 * PLANE; }
  else              { c0 = 2 * NCH;              cnt = 20; dst = out + 4 * PLANE; }

  const float* p = part + t + (size_t)c0 * PLANE;
  float s[10] = {};
  for (int c = 0; c < cnt; c += 10) {
#pragma unroll
    for (int u = 0; u < 10; ++u) s[u] += p[(size_t)(c + u) * PLANE];
  }
  float tot = ((s[0] + s[1]) + (s[2] + s[3])) + ((s[4] + s[5]) + (s[6] + s[7])) +
              (s[8] + s[9]);
  atomicAdd(&dst[t], tot);
}

extern "C" void kernel_launch(void* const* d_in, const int* in_sizes, int n_in,
                              void* d_out, int out_size, void* d_ws, size_t ws_size,
                              hipStream_t stream) {
  // input order per setup_inputs(): N, C, O, CB, H, gaussian_weights, hb_min, hb_max
  const float* cO  = (const float*)d_in[2];
  const float* cCB = (const float*)d_in[3];
  const float* cH  = (const float*)d_in[4];
  const float* gw  = (const float*)d_in[5];
  const float* hmn = (const float*)d_in[6];
  const float* hmx = (const float*)d_in[7];
  float* out  = (float*)d_out;
  float* part = (float*)d_ws;

  const size_t need = (size_t)(2 * NCH + NHP) * PLANE * sizeof(float); // 23 MB

  // out is zeroed every call (N and C planes are exactly zero: K_ANG_HB_GEN==0;
  // reduce/atomics accumulate into the rest). 360 KB -> negligible.
  (void)hipMemsetAsync(out, 0, (size_t)out_size * sizeof(float), stream);

  if (ws_size >= need) {
    force_fused<true><<<dim3(5 * NCH), dim3(256), 0, stream>>>(
        cO, cCB, cH, gw, hmn, hmx, out, part);
    reduce_seg<<<dim3(7 * NRED), dim3(256), 0, stream>>>(part, out);
  } else {
    force_fused<false><<<dim3(5 * NCH), dim3(256), 0, stream>>>(
        cO, cCB, cH, gw, hmn, hmx, out, nullptr);
  }
}